// Round 1
// baseline (306.904 us; speedup 1.0000x reference)
//
#include <hip/hip_runtime.h>
#include <hip/hip_bf16.h>
#include <math.h>

typedef __bf16 bf16v8 __attribute__((ext_vector_type(8)));
typedef float  f32x4  __attribute__((ext_vector_type(4)));

__device__ __forceinline__ unsigned pack_bf16(float lo, float hi) {
    unsigned short l = __builtin_bit_cast(unsigned short, (__bf16)lo);
    unsigned short h = __builtin_bit_cast(unsigned short, (__bf16)hi);
    return ((unsigned)h << 16) | (unsigned)l;
}

// ---------------------------------------------------------------------------
// Kernel 1: W_img (2048x512 f32, k-major) -> Wt (512x2048 bf16, a-major)
// ---------------------------------------------------------------------------
__global__ __launch_bounds__(256) void wt_k(const float* __restrict__ W,
                                            unsigned short* __restrict__ Wt)
{
    __shared__ float tile[64][65];
    const int k0 = blockIdx.x * 64;
    const int a0 = blockIdx.y * 64;
    const int t = threadIdx.x;
    const int c = t & 63, rbase = t >> 6;   // rbase 0..3
#pragma unroll
    for (int i = 0; i < 16; ++i) {
        int kr = rbase + i * 4;
        tile[kr][c] = W[(k0 + kr) * 512 + a0 + c];
    }
    __syncthreads();
#pragma unroll
    for (int i = 0; i < 16; ++i) {
        int ar = rbase + i * 4;
        Wt[(a0 + ar) * 2048 + k0 + c] =
            __builtin_bit_cast(unsigned short, (__bf16)tile[c][ar]);
    }
}

// ---------------------------------------------------------------------------
// Kernel 2: hb[b][a] = hidden[b]@W_hid[:,a] + b_hid[a] + b_img[a];
//           beta[b] = sigmoid(hidden[b]@w_beta + b_beta)
// ---------------------------------------------------------------------------
__global__ __launch_bounds__(256) void hid_k(
    const float* __restrict__ hidden, const float* __restrict__ W_hid,
    const float* __restrict__ b_hid,  const float* __restrict__ b_img,
    const float* __restrict__ w_beta, const float* __restrict__ b_beta,
    float* __restrict__ hb, float* __restrict__ betap)
{
    const int b = blockIdx.x, t = threadIdx.x;
    __shared__ float hs[512];
    __shared__ float red[4];
    hs[t]       = hidden[b * 512 + t];
    hs[t + 256] = hidden[b * 512 + 256 + t];
    __syncthreads();
    float a0 = 0.f, a1 = 0.f;
#pragma unroll 4
    for (int h = 0; h < 512; ++h) {
        float hv = hs[h];
        a0 = fmaf(hv, W_hid[h * 512 + t], a0);
        a1 = fmaf(hv, W_hid[h * 512 + 256 + t], a1);
    }
    hb[b * 512 + t]       = a0 + b_hid[t]       + b_img[t];
    hb[b * 512 + 256 + t] = a1 + b_hid[256 + t] + b_img[256 + t];

    float x = hs[t] * w_beta[t] + hs[t + 256] * w_beta[t + 256];
#pragma unroll
    for (int k = 32; k >= 1; k >>= 1) x += __shfl_xor(x, k, 64);
    const int lane = t & 63, wid = t >> 6;
    if (lane == 0) red[wid] = x;
    __syncthreads();
    if (t == 0) {
        float s = red[0] + red[1] + red[2] + red[3] + b_beta[0];
        betap[b] = 1.f / (1.f + __expf(-s));
    }
}

// ---------------------------------------------------------------------------
// Kernel 3: fused scores GEMM.
//   For M-tile (128 rows of img) x col-block (128 of A=512):
//   acc = img_tile @ Wt_tile^T (bf16 MFMA, fp32 acc), then
//   partial_scores[cb][row] = sum_col relu(acc + hb[b][col]) * w_att[col]
// ---------------------------------------------------------------------------
#define BM 128
#define BN 128
#define BK 32
#define NKIT 64   // 2048 / 32

__global__ __launch_bounds__(256, 2) void scores_gemm(
    const float* __restrict__ img,            // [25088][2048] f32
    const unsigned short* __restrict__ Wt,    // [512][2048] bf16 bits
    const float* __restrict__ hb,             // [128][512]
    const float* __restrict__ w_att,          // [512]
    float* __restrict__ partials)             // [4][25088]
{
    __shared__ __align__(16) char smem[32768];  // As[2][128][64B] + Bs[2][128][64B]
    char* As = smem;
    char* Bs = smem + 16384;

    const int tid  = threadIdx.x;
    const int lane = tid & 63;
    const int wid  = tid >> 6;
    const int wm   = wid >> 1;   // 0..1  (M half of 128)
    const int wn   = wid & 1;    // 0..1  (N half of 128)

    // XCD-bijective swizzle: 784 = 8 * 98, col-block fastest within an XCD chunk
    const int id = blockIdx.x;
    const int wg = (id & 7) * 98 + (id >> 3);
    const int cb    = wg & 3;      // col block 0..3
    const int mtile = wg >> 2;     // 0..195
    const int r0 = mtile * BM;
    const int a0 = cb * BN;

    // staging mapping: thread -> (row 0..127, k-half 0/1); same for A and B
    const int srow = tid >> 1;
    const int skh  = tid & 1;
    const int swzS = ((srow >> 1) & 3) << 4;

    const float*          ga = img + (r0 + srow) * 2048 + skh * 16;
    const unsigned short* gb = Wt  + (a0 + srow) * 2048 + skh * 16;

    const int g  = lane >> 4;   // k-group 0..3
    const int fl = lane & 15;

    f32x4 acc[4][4] = {};

    float4 areg[4];
    uint4  breg[2];
    {
        const float4* pa4 = (const float4*)ga;
        areg[0] = pa4[0]; areg[1] = pa4[1]; areg[2] = pa4[2]; areg[3] = pa4[3];
        const uint4* pb4 = (const uint4*)gb;
        breg[0] = pb4[0]; breg[1] = pb4[1];
    }

    for (int it = 0; it < NKIT; ++it) {
        const int bsel = it & 1;
        char* as = As + bsel * 8192;
        char* bs = Bs + bsel * 8192;

        // ---- write phase: convert A fp32->bf16, store A & B swizzled ----
        {
            float af[16];
            *(float4*)(af + 0)  = areg[0];
            *(float4*)(af + 4)  = areg[1];
            *(float4*)(af + 8)  = areg[2];
            *(float4*)(af + 12) = areg[3];
            uint4 c0, c1;
            c0.x = pack_bf16(af[0],  af[1]);  c0.y = pack_bf16(af[2],  af[3]);
            c0.z = pack_bf16(af[4],  af[5]);  c0.w = pack_bf16(af[6],  af[7]);
            c1.x = pack_bf16(af[8],  af[9]);  c1.y = pack_bf16(af[10], af[11]);
            c1.z = pack_bf16(af[12], af[13]); c1.w = pack_bf16(af[14], af[15]);
            char* wa = as + srow * 64;
            *(uint4*)(wa + ((skh * 32 + 0)  ^ swzS)) = c0;
            *(uint4*)(wa + ((skh * 32 + 16) ^ swzS)) = c1;
            char* wb = bs + srow * 64;
            *(uint4*)(wb + ((skh * 32 + 0)  ^ swzS)) = breg[0];
            *(uint4*)(wb + ((skh * 32 + 16) ^ swzS)) = breg[1];
        }
        __syncthreads();

        // ---- issue next tile's global loads early (hide under MFMA) ----
        if (it + 1 < NKIT) {
            ga += BK; gb += BK;
            const float4* pa4 = (const float4*)ga;
            areg[0] = pa4[0]; areg[1] = pa4[1]; areg[2] = pa4[2]; areg[3] = pa4[3];
            const uint4* pb4 = (const uint4*)gb;
            breg[0] = pb4[0]; breg[1] = pb4[1];
        }

        // ---- read fragments + MFMA ----
        bf16v8 av[4], bv[4];
#pragma unroll
        for (int fm = 0; fm < 4; ++fm) {
            int row = wm * 64 + fm * 16 + fl;
            av[fm] = *(const bf16v8*)(as + row * 64 + ((g * 16) ^ (((row >> 1) & 3) << 4)));
        }
#pragma unroll
        for (int fn = 0; fn < 4; ++fn) {
            int col = wn * 64 + fn * 16 + fl;
            bv[fn] = *(const bf16v8*)(bs + col * 64 + ((g * 16) ^ (((col >> 1) & 3) << 4)));
        }
#pragma unroll
        for (int fm = 0; fm < 4; ++fm)
#pragma unroll
            for (int fn = 0; fn < 4; ++fn)
                acc[fm][fn] = __builtin_amdgcn_mfma_f32_16x16x32_bf16(
                    av[fm], bv[fn], acc[fm][fn], 0, 0, 0);
    }

    // ---- epilogue: relu(acc + hb) * w_att, reduce over columns ----
    __syncthreads();
    float* red = (float*)smem;   // [2][128]
    const int l4 = lane >> 4;

    float w4[4];
#pragma unroll
    for (int fn = 0; fn < 4; ++fn) w4[fn] = w_att[a0 + wn * 64 + fn * 16 + fl];

#pragma unroll
    for (int fm = 0; fm < 4; ++fm) {
#pragma unroll
        for (int rg = 0; rg < 4; ++rg) {
            int row = wm * 64 + fm * 16 + l4 * 4 + rg;
            int grow = r0 + row;
            int bb = grow / 196;
            const float* hbrow = hb + bb * 512 + a0 + wn * 64;
            float s = 0.f;
#pragma unroll
            for (int fn = 0; fn < 4; ++fn) {
                float v = acc[fm][fn][rg] + hbrow[fn * 16 + fl];
                v = fmaxf(v, 0.f);
                s = fmaf(v, w4[fn], s);
            }
#pragma unroll
            for (int m = 1; m < 16; m <<= 1) s += __shfl_xor(s, m, 64);
            if (fl == 0) red[wn * 128 + row] = s;
        }
    }
    __syncthreads();
    if (tid < 128) {
        partials[cb * 25088 + r0 + tid] = red[tid] + red[128 + tid];
    }
}

// ---------------------------------------------------------------------------
// Kernel 4: softmax over N=196 per batch; writes attention_weights output and
//           beta-scaled weights for the context pass.
// ---------------------------------------------------------------------------
__global__ __launch_bounds__(256) void softmax_k(
    const float* __restrict__ partials, const float* __restrict__ betap,
    const float* __restrict__ b_att,
    float* __restrict__ out_w, float* __restrict__ wbeta)
{
    const int b = blockIdx.x;
    const int t = threadIdx.x;
    const int lane = t & 63, wid = t >> 6;
    __shared__ float red[4];

    float scv = 0.f, sc = -1e30f;
    if (t < 196) {
        int r = b * 196 + t;
        scv = partials[r] + partials[25088 + r] + partials[2 * 25088 + r] +
              partials[3 * 25088 + r] + b_att[0];
        sc = scv;
    }
    float m = sc;
#pragma unroll
    for (int k = 32; k >= 1; k >>= 1) m = fmaxf(m, __shfl_xor(m, k, 64));
    if (lane == 0) red[wid] = m;
    __syncthreads();
    m = fmaxf(fmaxf(red[0], red[1]), fmaxf(red[2], red[3]));

    float e = (t < 196) ? __expf(scv - m) : 0.f;
    float ssum = e;
#pragma unroll
    for (int k = 32; k >= 1; k >>= 1) ssum += __shfl_xor(ssum, k, 64);
    __syncthreads();
    if (lane == 0) red[wid] = ssum;
    __syncthreads();
    float denom = red[0] + red[1] + red[2] + red[3];

    if (t < 196) {
        float w = e / denom;
        out_w[b * 196 + t] = w;
        wbeta[b * 196 + t] = w * betap[b];
    }
}

// ---------------------------------------------------------------------------
// Kernel 5: context[b][c] = sum_n wbeta[b][n] * img[b][n][c]
// ---------------------------------------------------------------------------
__global__ __launch_bounds__(256) void ctx_k(
    const float* __restrict__ img, const float* __restrict__ wbeta,
    float* __restrict__ out)
{
    const int b = blockIdx.y;
    const int c0 = blockIdx.x * 1024 + threadIdx.x * 4;
    __shared__ float w[196];
    if (threadIdx.x < 196) w[threadIdx.x] = wbeta[b * 196 + threadIdx.x];
    __syncthreads();
    const float* base = img + (long)b * 196 * 2048 + c0;
    float4 acc = {0.f, 0.f, 0.f, 0.f};
#pragma unroll 4
    for (int n = 0; n < 196; ++n) {
        float4 v = *(const float4*)(base + n * 2048);
        float wn = w[n];
        acc.x = fmaf(wn, v.x, acc.x);
        acc.y = fmaf(wn, v.y, acc.y);
        acc.z = fmaf(wn, v.z, acc.z);
        acc.w = fmaf(wn, v.w, acc.w);
    }
    *(float4*)(out + b * 2048 + c0) = acc;
}

// ---------------------------------------------------------------------------
extern "C" void kernel_launch(void* const* d_in, const int* in_sizes, int n_in,
                              void* d_out, int out_size, void* d_ws, size_t ws_size,
                              hipStream_t stream)
{
    const float* img    = (const float*)d_in[0];
    const float* hidden = (const float*)d_in[1];
    const float* W_img  = (const float*)d_in[2];
    const float* b_img  = (const float*)d_in[3];
    const float* W_hid  = (const float*)d_in[4];
    const float* b_hid  = (const float*)d_in[5];
    const float* w_att  = (const float*)d_in[6];
    const float* b_att  = (const float*)d_in[7];
    const float* w_beta = (const float*)d_in[8];
    const float* b_beta = (const float*)d_in[9];

    char* ws = (char*)d_ws;
    unsigned short* Wt = (unsigned short*)ws;            // [512][2048] bf16: 2 MB
    float* hbp   = (float*)(ws + 2097152);               // [128][512]  : 256 KB
    float* betap = (float*)(ws + 2359296);               // [128]       : 512 B
    float* parts = (float*)(ws + 2359808);               // [4][25088]  : 392 KB
    float* wbeta = (float*)(ws + 2761216);               // [128][196]  : 98 KB

    float* out_ctx = (float*)d_out;                      // [128][2048]
    float* out_w   = out_ctx + 128 * 2048;               // [128][196]

    wt_k<<<dim3(32, 8), 256, 0, stream>>>(W_img, Wt);
    hid_k<<<128, 256, 0, stream>>>(hidden, W_hid, b_hid, b_img, w_beta, b_beta,
                                   hbp, betap);
    scores_gemm<<<784, 256, 0, stream>>>(img, Wt, hbp, w_att, parts);
    softmax_k<<<128, 256, 0, stream>>>(parts, betap, b_att, out_w, wbeta);
    ctx_k<<<dim3(2, 128), 256, 0, stream>>>(img, wbeta, out_ctx);
}

// Round 2
// 195.075 us; speedup vs baseline: 1.5733x; 1.5733x over previous
//
#include <hip/hip_runtime.h>
#include <hip/hip_bf16.h>
#include <math.h>

typedef __bf16 bf16v8 __attribute__((ext_vector_type(8)));
typedef float  f32x4  __attribute__((ext_vector_type(4)));

__device__ __forceinline__ void gload_lds16(const void* g, void* l) {
    __builtin_amdgcn_global_load_lds(
        (const __attribute__((address_space(1))) unsigned int*)g,
        (__attribute__((address_space(3))) unsigned int*)l, 16, 0, 0);
}

// ---------------------------------------------------------------------------
// Kernel 1: W_img (2048x512 f32, k-major) -> Wt (512x2048 bf16, a-major)
// ---------------------------------------------------------------------------
__global__ __launch_bounds__(256) void wt_k(const float* __restrict__ W,
                                            unsigned short* __restrict__ Wt)
{
    __shared__ float tile[64][65];
    const int k0 = blockIdx.x * 64;
    const int a0 = blockIdx.y * 64;
    const int t = threadIdx.x;
    const int c = t & 63, rbase = t >> 6;
#pragma unroll
    for (int i = 0; i < 16; ++i) {
        int kr = rbase + i * 4;
        tile[kr][c] = W[(k0 + kr) * 512 + a0 + c];
    }
    __syncthreads();
#pragma unroll
    for (int i = 0; i < 16; ++i) {
        int ar = rbase + i * 4;
        Wt[(a0 + ar) * 2048 + k0 + c] =
            __builtin_bit_cast(unsigned short, (__bf16)tile[c][ar]);
    }
}

// ---------------------------------------------------------------------------
// Kernel 2: hb[b][a] = hidden[b]@W_hid[:,a] + b_hid[a] + b_img[a];
//           beta[b] = sigmoid(hidden[b]@w_beta + b_beta)
// ---------------------------------------------------------------------------
__global__ __launch_bounds__(256) void hid_k(
    const float* __restrict__ hidden, const float* __restrict__ W_hid,
    const float* __restrict__ b_hid,  const float* __restrict__ b_img,
    const float* __restrict__ w_beta, const float* __restrict__ b_beta,
    float* __restrict__ hb, float* __restrict__ betap)
{
    const int b = blockIdx.x, t = threadIdx.x;
    __shared__ float hs[512];
    __shared__ float red[4];
    hs[t]       = hidden[b * 512 + t];
    hs[t + 256] = hidden[b * 512 + 256 + t];
    __syncthreads();
    float a0 = 0.f, a1 = 0.f;
#pragma unroll 4
    for (int h = 0; h < 512; ++h) {
        float hv = hs[h];
        a0 = fmaf(hv, W_hid[h * 512 + t], a0);
        a1 = fmaf(hv, W_hid[h * 512 + 256 + t], a1);
    }
    hb[b * 512 + t]       = a0 + b_hid[t]       + b_img[t];
    hb[b * 512 + 256 + t] = a1 + b_hid[256 + t] + b_img[256 + t];

    float x = hs[t] * w_beta[t] + hs[t + 256] * w_beta[t + 256];
#pragma unroll
    for (int k = 32; k >= 1; k >>= 1) x += __shfl_xor(x, k, 64);
    const int lane = t & 63, wid = t >> 6;
    if (lane == 0) red[wid] = x;
    __syncthreads();
    if (t == 0) {
        float s = red[0] + red[1] + red[2] + red[3] + b_beta[0];
        betap[b] = 1.f / (1.f + __expf(-s));
    }
}

// ---------------------------------------------------------------------------
// Kernel 3: fused scores GEMM (m97-style: global_load_lds staging, 2-phase).
//   A tile: fp32 [128 rows][32 k] in LDS (XOR-swizzled via source address),
//   converted to bf16 at fragment-read time. B tile: bf16 [128 cols][32 k].
//   Epilogue: partial_scores[cb][row] = sum_col relu(acc + hb) * w_att.
// ---------------------------------------------------------------------------
#define NKIT 64   // 2048 / 32

__global__ __launch_bounds__(256) void scores_gemm(
    const float* __restrict__ img,            // [25088][2048] f32
    const unsigned short* __restrict__ Wt,    // [512][2048] bf16 bits
    const float* __restrict__ hb,             // [128][512]
    const float* __restrict__ w_att,          // [512]
    float* __restrict__ partials)             // [4][25088]
{
    __shared__ __align__(16) char smem[49152]; // As[2][16K] + Bs[2][8K]
    char* As = smem;
    char* Bs = smem + 32768;

    const int tid  = threadIdx.x;
    const int lane = tid & 63;
    const int wid  = tid >> 6;
    const int wm   = wid >> 1;   // 0..1
    const int wn   = wid & 1;    // 0..1

    // XCD-bijective swizzle: 784 = 8*98; 4 col-blocks of one mtile land on
    // the same XCD consecutively so the img tile stays in that XCD's L2.
    const int id = blockIdx.x;
    const int wg = (id & 7) * 98 + (id >> 3);
    const int cb    = wg & 3;
    const int mtile = wg >> 2;
    const int r0 = mtile * 128;
    const int a0 = cb * 128;

    // --- per-lane staging source addresses (pre-swizzled, m173 pattern) ---
    // A: LDS linear pos p = chunk*1024 + lane*16; row = p>>7; swz=(row&7)<<4
    const float* gA[4];
#pragma unroll
    for (int r = 0; r < 4; ++r) {
        int row = (wid * 4 + r) * 8 + (lane >> 3);
        gA[r] = img + (size_t)(r0 + row) * 2048 + (((lane & 7) ^ (lane >> 3)) << 2);
    }
    // B: p = chunk*1024 + lane*16; col = p>>6; swz=(col&3)<<4
    const unsigned short* gB[2];
#pragma unroll
    for (int r = 0; r < 2; ++r) {
        int col = (wid * 2 + r) * 16 + (lane >> 2);
        gB[r] = Wt + (size_t)(a0 + col) * 2048 +
                (((lane & 3) ^ ((lane >> 2) & 3)) << 3);
    }

    const int g  = lane >> 4;   // k-group 0..3
    const int fl = lane & 15;

    f32x4 acc[4][4] = {};

    // prologue: stage tile 0 into buffer 0
    {
        char* asn = As + (wid * 4) * 1024;
        char* bsn = Bs + (wid * 2) * 1024;
#pragma unroll
        for (int r = 0; r < 4; ++r) gload_lds16(gA[r], asn + r * 1024);
#pragma unroll
        for (int r = 0; r < 2; ++r) gload_lds16(gB[r], bsn + r * 1024);
    }
    __syncthreads();

    for (int it = 0; it < NKIT; ++it) {
        const int bsel = it & 1;
        // ---- issue next tile's staging (async, drains at next barrier) ----
        if (it + 1 < NKIT) {
            char* asn = As + (bsel ^ 1) * 16384 + (wid * 4) * 1024;
            char* bsn = Bs + (bsel ^ 1) * 8192  + (wid * 2) * 1024;
#pragma unroll
            for (int r = 0; r < 4; ++r)
                gload_lds16(gA[r] + (it + 1) * 32, asn + r * 1024);
#pragma unroll
            for (int r = 0; r < 2; ++r)
                gload_lds16(gB[r] + (it + 1) * 32, bsn + r * 1024);
        }

        // ---- fragments from current buffer + MFMA ----
        char* asw = As + bsel * 16384;
        char* bsw = Bs + bsel * 8192;

        bf16v8 av[4], bv[4];
#pragma unroll
        for (int fm = 0; fm < 4; ++fm) {
            int row = wm * 64 + fm * 16 + fl;
            const char* pa = asw + row * 128;
            int sw = (fl & 7) << 4;
            f32x4 lo = *(const f32x4*)(pa + ((g * 32) ^ sw));
            f32x4 hi = *(const f32x4*)(pa + ((g * 32 + 16) ^ sw));
            bf16v8 a;
            a[0] = (__bf16)lo[0]; a[1] = (__bf16)lo[1];
            a[2] = (__bf16)lo[2]; a[3] = (__bf16)lo[3];
            a[4] = (__bf16)hi[0]; a[5] = (__bf16)hi[1];
            a[6] = (__bf16)hi[2]; a[7] = (__bf16)hi[3];
            av[fm] = a;
        }
#pragma unroll
        for (int fn = 0; fn < 4; ++fn) {
            int col = wn * 64 + fn * 16 + fl;
            bv[fn] = *(const bf16v8*)(bsw + col * 64 + ((g * 16) ^ ((fl & 3) << 4)));
        }
#pragma unroll
        for (int fm = 0; fm < 4; ++fm)
#pragma unroll
            for (int fn = 0; fn < 4; ++fn)
                acc[fm][fn] = __builtin_amdgcn_mfma_f32_16x16x32_bf16(
                    av[fm], bv[fn], acc[fm][fn], 0, 0, 0);

        __syncthreads();   // drains vmcnt(0): next buffer staged & safe
    }

    // ---- epilogue: relu(acc + hb) * w_att, reduce over columns ----
    float* red = (float*)smem;   // [2][128]
    const int l4 = lane >> 4;

    float w4[4];
#pragma unroll
    for (int fn = 0; fn < 4; ++fn) w4[fn] = w_att[a0 + wn * 64 + fn * 16 + fl];

#pragma unroll
    for (int fm = 0; fm < 4; ++fm) {
#pragma unroll
        for (int rg = 0; rg < 4; ++rg) {
            int row = wm * 64 + fm * 16 + l4 * 4 + rg;
            int grow = r0 + row;
            int bb = grow / 196;
            const float* hbrow = hb + bb * 512 + a0 + wn * 64;
            float s = 0.f;
#pragma unroll
            for (int fn = 0; fn < 4; ++fn) {
                float v = acc[fm][fn][rg] + hbrow[fn * 16 + fl];
                v = fmaxf(v, 0.f);
                s = fmaf(v, w4[fn], s);
            }
#pragma unroll
            for (int m = 1; m < 16; m <<= 1) s += __shfl_xor(s, m, 64);
            if (fl == 0) red[wn * 128 + row] = s;
        }
    }
    __syncthreads();
    if (tid < 128) {
        partials[cb * 25088 + r0 + tid] = red[tid] + red[128 + tid];
    }
}

// ---------------------------------------------------------------------------
// Kernel 4: softmax over N=196 per batch.
// ---------------------------------------------------------------------------
__global__ __launch_bounds__(256) void softmax_k(
    const float* __restrict__ partials, const float* __restrict__ betap,
    const float* __restrict__ b_att,
    float* __restrict__ out_w, float* __restrict__ wbeta)
{
    const int b = blockIdx.x;
    const int t = threadIdx.x;
    const int lane = t & 63, wid = t >> 6;
    __shared__ float red[4];

    float scv = 0.f, sc = -1e30f;
    if (t < 196) {
        int r = b * 196 + t;
        scv = partials[r] + partials[25088 + r] + partials[2 * 25088 + r] +
              partials[3 * 25088 + r] + b_att[0];
        sc = scv;
    }
    float m = sc;
#pragma unroll
    for (int k = 32; k >= 1; k >>= 1) m = fmaxf(m, __shfl_xor(m, k, 64));
    if (lane == 0) red[wid] = m;
    __syncthreads();
    m = fmaxf(fmaxf(red[0], red[1]), fmaxf(red[2], red[3]));

    float e = (t < 196) ? __expf(scv - m) : 0.f;
    float ssum = e;
#pragma unroll
    for (int k = 32; k >= 1; k >>= 1) ssum += __shfl_xor(ssum, k, 64);
    __syncthreads();
    if (lane == 0) red[wid] = ssum;
    __syncthreads();
    float denom = red[0] + red[1] + red[2] + red[3];

    if (t < 196) {
        float w = e / denom;
        out_w[b * 196 + t] = w;
        wbeta[b * 196 + t] = w * betap[b];
    }
}

// ---------------------------------------------------------------------------
// Kernel 5: context[b][c] = sum_n wbeta[b][n] * img[b][n][c]
// ---------------------------------------------------------------------------
__global__ __launch_bounds__(256) void ctx_k(
    const float* __restrict__ img, const float* __restrict__ wbeta,
    float* __restrict__ out)
{
    const int b = blockIdx.y;
    const int c0 = blockIdx.x * 512 + threadIdx.x * 2;
    __shared__ float w[200];
    if (threadIdx.x < 196) w[threadIdx.x] = wbeta[b * 196 + threadIdx.x];
    __syncthreads();
    const float* base = img + (size_t)b * 196 * 2048 + c0;
    float acx = 0.f, acy = 0.f;
#pragma unroll 4
    for (int n = 0; n < 196; ++n) {
        float2 v = *(const float2*)(base + (size_t)n * 2048);
        float wn = w[n];
        acx = fmaf(wn, v.x, acx);
        acy = fmaf(wn, v.y, acy);
    }
    float2 r; r.x = acx; r.y = acy;
    *(float2*)(out + b * 2048 + c0) = r;
}

// ---------------------------------------------------------------------------
extern "C" void kernel_launch(void* const* d_in, const int* in_sizes, int n_in,
                              void* d_out, int out_size, void* d_ws, size_t ws_size,
                              hipStream_t stream)
{
    const float* img    = (const float*)d_in[0];
    const float* hidden = (const float*)d_in[1];
    const float* W_img  = (const float*)d_in[2];
    const float* b_img  = (const float*)d_in[3];
    const float* W_hid  = (const float*)d_in[4];
    const float* b_hid  = (const float*)d_in[5];
    const float* w_att  = (const float*)d_in[6];
    const float* b_att  = (const float*)d_in[7];
    const float* w_beta = (const float*)d_in[8];
    const float* b_beta = (const float*)d_in[9];

    char* ws = (char*)d_ws;
    unsigned short* Wt = (unsigned short*)ws;            // [512][2048] bf16: 2 MB
    float* hbp   = (float*)(ws + 2097152);               // [128][512]
    float* betap = (float*)(ws + 2359296);               // [128]
    float* parts = (float*)(ws + 2359808);               // [4][25088]
    float* wbeta = (float*)(ws + 2761216);               // [128][196]

    float* out_ctx = (float*)d_out;                      // [128][2048]
    float* out_w   = out_ctx + 128 * 2048;               // [128][196]

    wt_k<<<dim3(32, 8), 256, 0, stream>>>(W_img, Wt);
    hid_k<<<128, 256, 0, stream>>>(hidden, W_hid, b_hid, b_img, w_beta, b_beta,
                                   hbp, betap);
    scores_gemm<<<784, 256, 0, stream>>>(img, Wt, hbp, w_att, parts);
    softmax_k<<<128, 256, 0, stream>>>(parts, betap, b_att, out_w, wbeta);
    ctx_k<<<dim3(4, 128), 256, 0, stream>>>(img, wbeta, out_ctx);
}